// Round 1
// baseline (5402.797 us; speedup 1.0000x reference)
//
#include <hip/hip_runtime.h>

namespace {

constexpr int BB = 2048;   // batch
constexpr int TT = 256;    // time steps
constexpr int H  = 64;     // hidden
constexpr int NB = 16;     // batch rows per block
constexpr int NTH = 256;   // threads per block

__device__ __forceinline__ float bf2f(unsigned short u) {
  return __uint_as_float(((unsigned int)u) << 16);
}
__device__ __forceinline__ unsigned short f2bf(float f) {
  unsigned int x = __float_as_uint(f);
  return (unsigned short)((x + 0x7fffu + ((x >> 16) & 1u)) >> 16);
}
__device__ __forceinline__ float sigm(float x) {
  return __builtin_amdgcn_rcpf(1.f + __expf(-x));
}
__device__ __forceinline__ float tanh_f(float x) {
  float e = __expf(2.f * x);
  return 1.f - 2.f * __builtin_amdgcn_rcpf(e + 1.f);
}

// ---------------- layer 0 (input dim 1 or 4) ----------------
__global__ __launch_bounds__(NTH) void gru_l0(
    const float* __restrict__ xs, const float* __restrict__ xp,
    const float* __restrict__ W0s, const float* __restrict__ W0p,
    const float* __restrict__ Whs, const float* __restrict__ Whp,
    const float* __restrict__ bis, const float* __restrict__ bhs,
    const float* __restrict__ bip, const float* __restrict__ bhp,
    unsigned short* __restrict__ bufs, unsigned short* __restrict__ bufp) {
  const int bid = blockIdx.x;
  const int stack = bid >> 7;            // 0 = sentiment, 1 = price
  const int b0 = (bid & 127) * NB;
  const float* x  = stack ? xp  : xs;
  const int in_dim = stack ? 4 : 1;
  const float* W0 = stack ? W0p : W0s;
  const float* Wh = stack ? Whp : Whs;
  const float* bi = stack ? bip : bis;
  const float* bh = stack ? bhp : bhs;
  unsigned short* buf = stack ? bufp : bufs;

  __shared__ float WH_T[H][192];      // Whh transposed: [k][j]
  __shared__ float W0_T[4][192];      // Wih0 transposed
  __shared__ float act_h[NB][H];
  __shared__ float act_x[NB][4];

  const int tid = threadIdx.x;
  for (int e = tid; e < 192 * H; e += NTH) {
    int j = e >> 6, k = e & 63;
    WH_T[k][j] = Wh[e];
  }
  for (int e = tid; e < 192 * in_dim; e += NTH) {
    int j = e / in_dim, d = e - j * in_dim;
    W0_T[d][j] = W0[e];
  }
  for (int e = tid; e < NB * H; e += NTH) ((float*)act_h)[e] = 0.f;

  const int tr  = tid & 63;
  const int tb4 = (tid >> 6) * 4;
  const float b_r  = bi[tr]       + bh[tr];
  const float b_z  = bi[64 + tr]  + bh[64 + tr];
  const float b_in = bi[128 + tr];
  const float b_hn = bh[128 + tr];

  float h[4] = {0.f, 0.f, 0.f, 0.f};
  const int nx = NB * in_dim;            // 16 or 64
  const int pb = (tid < nx) ? (tid / in_dim) : 0;
  const int pd = (tid < nx) ? (tid % in_dim) : 0;
  float pxv = 0.f;
  if (tid < nx) pxv = x[(size_t)(b0 + pb) * TT * in_dim + pd];

  __syncthreads();
  for (int t = 0; t < TT; ++t) {
    if (tid < nx) act_x[pb][pd] = pxv;
    #pragma unroll
    for (int b = 0; b < 4; ++b) act_h[tb4 + b][tr] = h[b];
    __syncthreads();
    if (t + 1 < TT && tid < nx)
      pxv = x[(size_t)(b0 + pb) * TT * in_dim + (size_t)(t + 1) * in_dim + pd];

    float hr[4] = {0.f,0.f,0.f,0.f}, hz[4] = {0.f,0.f,0.f,0.f}, hn[4] = {0.f,0.f,0.f,0.f};
    #pragma unroll 8
    for (int k = 0; k < H; ++k) {
      float wr = WH_T[k][tr], wz = WH_T[k][64 + tr], wn = WH_T[k][128 + tr];
      #pragma unroll
      for (int b = 0; b < 4; ++b) {
        float a = act_h[tb4 + b][k];
        hr[b] = fmaf(wr, a, hr[b]);
        hz[b] = fmaf(wz, a, hz[b]);
        hn[b] = fmaf(wn, a, hn[b]);
      }
    }
    float xr[4] = {0.f,0.f,0.f,0.f}, xz[4] = {0.f,0.f,0.f,0.f}, xn[4] = {0.f,0.f,0.f,0.f};
    for (int d = 0; d < in_dim; ++d) {
      float wr = W0_T[d][tr], wz = W0_T[d][64 + tr], wn = W0_T[d][128 + tr];
      #pragma unroll
      for (int b = 0; b < 4; ++b) {
        float a = act_x[tb4 + b][d];
        xr[b] = fmaf(wr, a, xr[b]);
        xz[b] = fmaf(wz, a, xz[b]);
        xn[b] = fmaf(wn, a, xn[b]);
      }
    }
    #pragma unroll
    for (int b = 0; b < 4; ++b) {
      float r = sigm(xr[b] + hr[b] + b_r);
      float z = sigm(xz[b] + hz[b] + b_z);
      float n = tanh_f(xn[b] + b_in + r * (hn[b] + b_hn));
      h[b] = (1.f - z) * n + z * h[b];
      buf[(size_t)(b0 + tb4 + b) * TT * H + (size_t)t * H + tr] = f2bf(h[b]);
    }
    __syncthreads();
  }
}

// ---------------- layers 1..3 (input dim 64, in-place on buf) ----------------
__global__ __launch_bounds__(NTH) void gru_ln(
    const float* __restrict__ Wxs, const float* __restrict__ Whs,
    const float* __restrict__ bis, const float* __restrict__ bhs,
    const float* __restrict__ Wxp, const float* __restrict__ Whp,
    const float* __restrict__ bip, const float* __restrict__ bhp,
    unsigned short* __restrict__ bufs, unsigned short* __restrict__ bufp,
    float* __restrict__ hlast, int write_y) {
  const int bid = blockIdx.x;
  const int stack = bid >> 7;
  const int b0 = (bid & 127) * NB;
  const float* Wx = stack ? Wxp : Wxs;
  const float* Wh = stack ? Whp : Whs;
  const float* bi = stack ? bip : bis;
  const float* bh = stack ? bhp : bhs;
  unsigned short* buf = stack ? bufp : bufs;

  __shared__ float WX_T[H][192];
  __shared__ float WH_T[H][192];
  __shared__ float act_x[NB][H];
  __shared__ float act_h[NB][H];

  const int tid = threadIdx.x;
  for (int e = tid; e < 192 * H; e += NTH) {
    int j = e >> 6, k = e & 63;
    WX_T[k][j] = Wx[e];
    WH_T[k][j] = Wh[e];
  }
  for (int e = tid; e < NB * H; e += NTH) ((float*)act_h)[e] = 0.f;

  const int tr  = tid & 63;
  const int tb4 = (tid >> 6) * 4;
  const float b_r  = bi[tr]       + bh[tr];
  const float b_z  = bi[64 + tr]  + bh[64 + tr];
  const float b_in = bi[128 + tr];
  const float b_hn = bh[128 + tr];

  float h[4] = {0.f, 0.f, 0.f, 0.f};
  const int pb = tid >> 4;          // 0..15
  const int pk = (tid & 15) * 4;    // 0,4,...,60
  ushort4 pxv = *(const ushort4*)(buf + (size_t)(b0 + pb) * TT * H + pk);

  __syncthreads();
  for (int t = 0; t < TT; ++t) {
    act_x[pb][pk + 0] = bf2f(pxv.x);
    act_x[pb][pk + 1] = bf2f(pxv.y);
    act_x[pb][pk + 2] = bf2f(pxv.z);
    act_x[pb][pk + 3] = bf2f(pxv.w);
    #pragma unroll
    for (int b = 0; b < 4; ++b) act_h[tb4 + b][tr] = h[b];
    __syncthreads();
    if (t + 1 < TT)
      pxv = *(const ushort4*)(buf + (size_t)(b0 + pb) * TT * H + (size_t)(t + 1) * H + pk);

    float xr[4] = {0.f,0.f,0.f,0.f}, xz[4] = {0.f,0.f,0.f,0.f}, xn[4] = {0.f,0.f,0.f,0.f};
    float hr[4] = {0.f,0.f,0.f,0.f}, hz[4] = {0.f,0.f,0.f,0.f}, hn[4] = {0.f,0.f,0.f,0.f};
    #pragma unroll 4
    for (int k = 0; k < H; ++k) {
      float wxr = WX_T[k][tr], wxz = WX_T[k][64 + tr], wxn = WX_T[k][128 + tr];
      float whr = WH_T[k][tr], whz = WH_T[k][64 + tr], whn = WH_T[k][128 + tr];
      #pragma unroll
      for (int b = 0; b < 4; ++b) {
        float ax = act_x[tb4 + b][k];
        float ah = act_h[tb4 + b][k];
        xr[b] = fmaf(wxr, ax, xr[b]);
        xz[b] = fmaf(wxz, ax, xz[b]);
        xn[b] = fmaf(wxn, ax, xn[b]);
        hr[b] = fmaf(whr, ah, hr[b]);
        hz[b] = fmaf(whz, ah, hz[b]);
        hn[b] = fmaf(whn, ah, hn[b]);
      }
    }
    #pragma unroll
    for (int b = 0; b < 4; ++b) {
      float r = sigm(xr[b] + hr[b] + b_r);
      float z = sigm(xz[b] + hz[b] + b_z);
      float n = tanh_f(xn[b] + b_in + r * (hn[b] + b_hn));
      h[b] = (1.f - z) * n + z * h[b];
      if (write_y) {
        buf[(size_t)(b0 + tb4 + b) * TT * H + (size_t)t * H + tr] = f2bf(h[b]);
      } else if (t == TT - 1) {
        hlast[(size_t)stack * BB * H + (size_t)(b0 + tb4 + b) * H + tr] = h[b];
      }
    }
    __syncthreads();
  }
}

// ---------------- FC head ----------------
__global__ __launch_bounds__(128) void head(
    const float* __restrict__ hlast,
    const float* __restrict__ W1, const float* __restrict__ b1,
    const float* __restrict__ g1, const float* __restrict__ be1,
    const float* __restrict__ m1, const float* __restrict__ v1,
    const float* __restrict__ W2, const float* __restrict__ b2,
    const float* __restrict__ g2, const float* __restrict__ be2,
    const float* __restrict__ m2, const float* __restrict__ v2,
    const float* __restrict__ W3, const float* __restrict__ b3,
    float* __restrict__ out) {
  const int b = blockIdx.x;
  const int j = threadIdx.x;
  __shared__ float xin[128];
  __shared__ float y1[128];
  __shared__ float y2[128];
  xin[j] = (j < 64) ? hlast[(size_t)b * H + j]
                    : hlast[(size_t)BB * H + (size_t)b * H + (j - 64)];
  __syncthreads();
  float acc = b1[j];
  #pragma unroll 8
  for (int k = 0; k < 128; ++k) acc = fmaf(W1[j * 128 + k], xin[k], acc);
  float sc = g1[j] * rsqrtf(v1[j] + 1e-5f);
  y1[j] = fmaxf(0.f, (acc - m1[j]) * sc + be1[j]);
  __syncthreads();
  acc = b2[j];
  #pragma unroll 8
  for (int k = 0; k < 128; ++k) acc = fmaf(W2[j * 128 + k], y1[k], acc);
  sc = g2[j] * rsqrtf(v2[j] + 1e-5f);
  y2[j] = fmaxf(0.f, (acc - m2[j]) * sc + be2[j]);
  __syncthreads();
  if (j < 2) {
    float a = b3[j];
    #pragma unroll 8
    for (int k = 0; k < 128; ++k) a = fmaf(W3[j * 128 + k], y2[k], a);
    out[(size_t)b * 2 + j] = a;
  }
}

}  // namespace

extern "C" void kernel_launch(void* const* d_in, const int* in_sizes, int n_in,
                              void* d_out, int out_size, void* d_ws, size_t ws_size,
                              hipStream_t stream) {
  (void)in_sizes; (void)n_in; (void)out_size; (void)ws_size;
  const float* sent   = (const float*)d_in[0];
  const float* price  = (const float*)d_in[1];
  const float* s_Wih0 = (const float*)d_in[2];
  const float* s_Wih  = (const float*)d_in[3];
  const float* s_Whh  = (const float*)d_in[4];
  const float* s_bih  = (const float*)d_in[5];
  const float* s_bhh  = (const float*)d_in[6];
  const float* p_Wih0 = (const float*)d_in[7];
  const float* p_Wih  = (const float*)d_in[8];
  const float* p_Whh  = (const float*)d_in[9];
  const float* p_bih  = (const float*)d_in[10];
  const float* p_bhh  = (const float*)d_in[11];
  const float* fc1_W  = (const float*)d_in[12];
  const float* fc1_b  = (const float*)d_in[13];
  const float* bn1_g  = (const float*)d_in[14];
  const float* bn1_b  = (const float*)d_in[15];
  const float* bn1_m  = (const float*)d_in[16];
  const float* bn1_v  = (const float*)d_in[17];
  const float* fc2_W  = (const float*)d_in[18];
  const float* fc2_b  = (const float*)d_in[19];
  const float* bn2_g  = (const float*)d_in[20];
  const float* bn2_b  = (const float*)d_in[21];
  const float* bn2_m  = (const float*)d_in[22];
  const float* bn2_v  = (const float*)d_in[23];
  const float* fc3_W  = (const float*)d_in[24];
  const float* fc3_b  = (const float*)d_in[25];
  float* out = (float*)d_out;

  unsigned short* bufs = (unsigned short*)d_ws;                 // [B,T,64] bf16
  unsigned short* bufp = bufs + (size_t)BB * TT * H;            // [B,T,64] bf16
  float* hlast = (float*)(bufp + (size_t)BB * TT * H);          // [2,B,64] f32

  gru_l0<<<dim3(256), dim3(NTH), 0, stream>>>(
      sent, price, s_Wih0, p_Wih0, s_Whh, p_Whh,
      s_bih, s_bhh, p_bih, p_bhh, bufs, bufp);

  for (int l = 1; l <= 3; ++l) {
    gru_ln<<<dim3(256), dim3(NTH), 0, stream>>>(
        s_Wih + (size_t)(l - 1) * 192 * H, s_Whh + (size_t)l * 192 * H,
        s_bih + l * 192, s_bhh + l * 192,
        p_Wih + (size_t)(l - 1) * 192 * H, p_Whh + (size_t)l * 192 * H,
        p_bih + l * 192, p_bhh + l * 192,
        bufs, bufp, hlast, (l < 3) ? 1 : 0);
  }

  head<<<dim3(BB), dim3(128), 0, stream>>>(
      hlast, fc1_W, fc1_b, bn1_g, bn1_b, bn1_m, bn1_v,
      fc2_W, fc2_b, bn2_g, bn2_b, bn2_m, bn2_v, fc3_W, fc3_b, out);
}

// Round 2
// 762.311 us; speedup vs baseline: 7.0874x; 7.0874x over previous
//
#include <hip/hip_runtime.h>

namespace {

constexpr int BB = 2048;   // batch
constexpr int TT = 256;    // time steps

typedef __attribute__((ext_vector_type(8))) short bf8;          // 8 bf16 (4 VGPR)
typedef __attribute__((ext_vector_type(4))) float f4;           // MFMA acc
typedef __attribute__((ext_vector_type(4))) unsigned short us4;

#define MFMA16(a, b, c) __builtin_amdgcn_mfma_f32_16x16x32_bf16((a), (b), (c), 0, 0, 0)

__device__ __forceinline__ unsigned short f2bf_rne(float f) {
  unsigned int x = __float_as_uint(f);
  return (unsigned short)((x + 0x7fffu + ((x >> 16) & 1u)) >> 16);
}
__device__ __forceinline__ float sigm(float x) {
  return __builtin_amdgcn_rcpf(1.f + __expf(-x));
}
__device__ __forceinline__ float tanh_f(float x) {
  float e = __expf(2.f * x);
  return 1.f - 2.f * __builtin_amdgcn_rcpf(e + 1.f);
}
// split a float into bf16 hi (truncated) + bf16 lo (residual); lo compensates hi's
// truncation so combined error ~2^-16 relative.
__device__ __forceinline__ void mk_hilo(float v, short& hi, short& lo) {
  unsigned int u = __float_as_uint(v);
  hi = (short)(u >> 16);
  float r = v - __uint_as_float(u & 0xffff0000u);
  lo = (short)(__float_as_uint(r) >> 16);
}

// ---------------- layers 1..3: full MFMA recurrence, in-place on buf ----------------
__global__ __launch_bounds__(256, 1) void gru_ln(
    const float* __restrict__ Wxs, const float* __restrict__ Whs,
    const float* __restrict__ bis, const float* __restrict__ bhs,
    const float* __restrict__ Wxp, const float* __restrict__ Whp,
    const float* __restrict__ bip, const float* __restrict__ bhp,
    unsigned short* __restrict__ buf, float* __restrict__ hlast, int write_y) {
  const int tid = threadIdx.x;
  const int w = tid >> 6, lane = tid & 63;
  const int n15 = lane & 15, g = lane >> 4;
  const int blk = blockIdx.x, stack = blk >> 7;
  const int b0 = (blk & 127) * 16;
  const float* Wx = stack ? Wxp : Wxs;
  const float* Wh = stack ? Whp : Whs;
  const float* bi = stack ? bip : bis;
  const float* bh = stack ? bhp : bhs;
  unsigned short* xb = buf + (size_t)blk * TT * 1024;  // [t][n][64] bf16

  __shared__ unsigned short hbuf[2][2][16][72];  // [phase][hi/lo][n][64+8pad]

  // ---- weight fragments in registers (A-frag: row = lane&15, k = g*8+j contiguous)
  bf8 wxh[3][2], wxl[3][2], whh[3][2], whl[3][2];
  const int mrow = 16 * w + n15;  // wave w owns Mtiles {w, 4+w, 8+w} -> units [16w,16w+16)
  #pragma unroll
  for (int i = 0; i < 3; ++i) {
    #pragma unroll
    for (int kt = 0; kt < 2; ++kt) {
      const float* px_ = Wx + (size_t)(i * 64 + mrow) * 64 + kt * 32 + g * 8;
      const float* ph_ = Wh + (size_t)(i * 64 + mrow) * 64 + kt * 32 + g * 8;
      f4 xa = *(const f4*)px_, xc = *(const f4*)(px_ + 4);
      f4 ha = *(const f4*)ph_, hc = *(const f4*)(ph_ + 4);
      bf8 h1, l1, h2, l2;
      #pragma unroll
      for (int j = 0; j < 8; ++j) {
        float vx = (j < 4) ? xa[j] : xc[j - 4];
        float vh = (j < 4) ? ha[j] : hc[j - 4];
        short a_, b_;
        mk_hilo(vx, a_, b_); h1[j] = a_; l1[j] = b_;
        mk_hilo(vh, a_, b_); h2[j] = a_; l2[j] = b_;
      }
      wxh[i][kt] = h1; wxl[i][kt] = l1; whh[i][kt] = h2; whl[i][kt] = l2;
    }
  }

  const int mu = 16 * w + 4 * g;  // C-layout unit base for this lane's 4 regs
  f4 bR, bZ, bNx, bNh;
  #pragma unroll
  for (int r = 0; r < 4; ++r) {
    bR[r]  = bi[mu + r] + bh[mu + r];
    bZ[r]  = bi[64 + mu + r] + bh[64 + mu + r];
    bNx[r] = bi[128 + mu + r];
    bNh[r] = bh[128 + mu + r];
  }

  f4 h = {0.f, 0.f, 0.f, 0.f};
  {
    us4 z4 = {0, 0, 0, 0};
    *(us4*)&hbuf[0][0][n15][mu] = z4;
    *(us4*)&hbuf[0][1][n15][mu] = z4;
  }
  // prefetch x B-frags for t=0 (B-frag: col = lane&15, k = g*8+j contiguous)
  bf8 xf0 = *(const bf8*)(xb + n15 * 64 + g * 8);
  bf8 xf1 = *(const bf8*)(xb + n15 * 64 + 32 + g * 8);
  __syncthreads();

  #pragma unroll 1
  for (int t = 0; t < TT; ++t) {
    bf8 xc0 = xf0, xc1 = xf1;
    if (t + 1 < TT) {
      xf0 = *(const bf8*)(xb + (size_t)(t + 1) * 1024 + n15 * 64 + g * 8);
      xf1 = *(const bf8*)(xb + (size_t)(t + 1) * 1024 + n15 * 64 + 32 + g * 8);
    }
    const int p = t & 1;
    bf8 hh0 = *(const bf8*)&hbuf[p][0][n15][g * 8];
    bf8 hh1 = *(const bf8*)&hbuf[p][0][n15][32 + g * 8];
    bf8 hl0 = *(const bf8*)&hbuf[p][1][n15][g * 8];
    bf8 hl1 = *(const bf8*)&hbuf[p][1][n15][32 + g * 8];

    f4 aR = bR, aZ = bZ, aNx = bNx, aNh = bNh;
    // x-part: (Wx_hi + Wx_lo) @ x
    aR  = MFMA16(wxh[0][0], xc0, aR);  aR  = MFMA16(wxh[0][1], xc1, aR);
    aZ  = MFMA16(wxh[1][0], xc0, aZ);  aZ  = MFMA16(wxh[1][1], xc1, aZ);
    aNx = MFMA16(wxh[2][0], xc0, aNx); aNx = MFMA16(wxh[2][1], xc1, aNx);
    aR  = MFMA16(wxl[0][0], xc0, aR);  aR  = MFMA16(wxl[0][1], xc1, aR);
    aZ  = MFMA16(wxl[1][0], xc0, aZ);  aZ  = MFMA16(wxl[1][1], xc1, aZ);
    aNx = MFMA16(wxl[2][0], xc0, aNx); aNx = MFMA16(wxl[2][1], xc1, aNx);
    // h-part: Wh_hi@h_hi + Wh_lo@h_hi + Wh_hi@h_lo
    aR  = MFMA16(whh[0][0], hh0, aR);  aR  = MFMA16(whh[0][1], hh1, aR);
    aZ  = MFMA16(whh[1][0], hh0, aZ);  aZ  = MFMA16(whh[1][1], hh1, aZ);
    aNh = MFMA16(whh[2][0], hh0, aNh); aNh = MFMA16(whh[2][1], hh1, aNh);
    aR  = MFMA16(whl[0][0], hh0, aR);  aR  = MFMA16(whl[0][1], hh1, aR);
    aZ  = MFMA16(whl[1][0], hh0, aZ);  aZ  = MFMA16(whl[1][1], hh1, aZ);
    aNh = MFMA16(whl[2][0], hh0, aNh); aNh = MFMA16(whl[2][1], hh1, aNh);
    aR  = MFMA16(whh[0][0], hl0, aR);  aR  = MFMA16(whh[0][1], hl1, aR);
    aZ  = MFMA16(whh[1][0], hl0, aZ);  aZ  = MFMA16(whh[1][1], hl1, aZ);
    aNh = MFMA16(whh[2][0], hl0, aNh); aNh = MFMA16(whh[2][1], hl1, aNh);

    #pragma unroll
    for (int r = 0; r < 4; ++r) {
      float rr = sigm(aR[r]);
      float zz = sigm(aZ[r]);
      float nn = tanh_f(aNx[r] + rr * aNh[r]);
      h[r] = nn + zz * (h[r] - nn);
    }

    us4 hiw, low;
    #pragma unroll
    for (int r = 0; r < 4; ++r) {
      unsigned int u = __float_as_uint(h[r]);
      hiw[r] = (unsigned short)(u >> 16);
      float res = h[r] - __uint_as_float(u & 0xffff0000u);
      low[r] = (unsigned short)(__float_as_uint(res) >> 16);
    }
    const int q = (t + 1) & 1;
    *(us4*)&hbuf[q][0][n15][mu] = hiw;
    *(us4*)&hbuf[q][1][n15][mu] = low;

    if (write_y) {
      us4 yw;
      #pragma unroll
      for (int r = 0; r < 4; ++r) yw[r] = f2bf_rne(h[r]);
      *(us4*)(xb + (size_t)t * 1024 + n15 * 64 + mu) = yw;
    } else if (t == TT - 1) {
      *(f4*)(hlast + ((size_t)stack * BB + b0 + n15) * 64 + mu) = h;
    }
    __syncthreads();
  }
}

// ---------------- layer 0: x-projection (K=1/4) via VALU, h via MFMA ----------------
__global__ __launch_bounds__(256, 1) void gru_l0(
    const float* __restrict__ xs, const float* __restrict__ xp,
    const float* __restrict__ W0s, const float* __restrict__ W0p,
    const float* __restrict__ Whs, const float* __restrict__ Whp,
    const float* __restrict__ bis, const float* __restrict__ bhs,
    const float* __restrict__ bip, const float* __restrict__ bhp,
    unsigned short* __restrict__ buf) {
  const int tid = threadIdx.x;
  const int w = tid >> 6, lane = tid & 63;
  const int n15 = lane & 15, g = lane >> 4;
  const int blk = blockIdx.x, stack = blk >> 7;
  const int b0 = (blk & 127) * 16;
  const float* W0 = stack ? W0p : W0s;
  const float* Wh = stack ? Whp : Whs;
  const float* bi = stack ? bip : bis;
  const float* bh = stack ? bhp : bhs;
  unsigned short* xb = buf + (size_t)blk * TT * 1024;

  __shared__ unsigned short hbuf[2][2][16][72];

  bf8 whh[3][2], whl[3][2];
  const int mrow = 16 * w + n15;
  #pragma unroll
  for (int i = 0; i < 3; ++i) {
    #pragma unroll
    for (int kt = 0; kt < 2; ++kt) {
      const float* ph_ = Wh + (size_t)(i * 64 + mrow) * 64 + kt * 32 + g * 8;
      f4 ha = *(const f4*)ph_, hc = *(const f4*)(ph_ + 4);
      bf8 h2, l2;
      #pragma unroll
      for (int j = 0; j < 8; ++j) {
        float vh = (j < 4) ? ha[j] : hc[j - 4];
        short a_, b_;
        mk_hilo(vh, a_, b_); h2[j] = a_; l2[j] = b_;
      }
      whh[i][kt] = h2; whl[i][kt] = l2;
    }
  }

  const int mu = 16 * w + 4 * g;
  f4 bR, bZ, bNx, bNh;
  float w0[3][4][4];
  #pragma unroll
  for (int i = 0; i < 3; ++i) {
    #pragma unroll
    for (int r = 0; r < 4; ++r) {
      const int m = i * 64 + mu + r;
      if (stack) {
        f4 t4 = *(const f4*)(W0 + (size_t)m * 4);
        w0[i][r][0] = t4[0]; w0[i][r][1] = t4[1]; w0[i][r][2] = t4[2]; w0[i][r][3] = t4[3];
      } else {
        w0[i][r][0] = W0[m]; w0[i][r][1] = 0.f; w0[i][r][2] = 0.f; w0[i][r][3] = 0.f;
      }
    }
  }
  #pragma unroll
  for (int r = 0; r < 4; ++r) {
    bR[r]  = bi[mu + r] + bh[mu + r];
    bZ[r]  = bi[64 + mu + r] + bh[64 + mu + r];
    bNx[r] = bi[128 + mu + r];
    bNh[r] = bh[128 + mu + r];
  }

  f4 h = {0.f, 0.f, 0.f, 0.f};
  {
    us4 z4 = {0, 0, 0, 0};
    *(us4*)&hbuf[0][0][n15][mu] = z4;
    *(us4*)&hbuf[0][1][n15][mu] = z4;
  }
  const size_t row = (size_t)(b0 + n15);
  float px[4];
  if (stack) {
    f4 t4 = *(const f4*)(xp + row * TT * 4);
    px[0] = t4[0]; px[1] = t4[1]; px[2] = t4[2]; px[3] = t4[3];
  } else {
    px[0] = xs[row * TT]; px[1] = px[2] = px[3] = 0.f;
  }
  __syncthreads();

  #pragma unroll 1
  for (int t = 0; t < TT; ++t) {
    float xc0 = px[0], xc1 = px[1], xc2 = px[2], xc3 = px[3];
    if (t + 1 < TT) {
      if (stack) {
        f4 t4 = *(const f4*)(xp + (row * TT + t + 1) * 4);
        px[0] = t4[0]; px[1] = t4[1]; px[2] = t4[2]; px[3] = t4[3];
      } else {
        px[0] = xs[row * TT + t + 1];
      }
    }
    const int p = t & 1;
    bf8 hh0 = *(const bf8*)&hbuf[p][0][n15][g * 8];
    bf8 hh1 = *(const bf8*)&hbuf[p][0][n15][32 + g * 8];
    bf8 hl0 = *(const bf8*)&hbuf[p][1][n15][g * 8];
    bf8 hl1 = *(const bf8*)&hbuf[p][1][n15][32 + g * 8];

    f4 aR = bR, aZ = bZ, aNx = bNx, aNh = bNh;
    #pragma unroll
    for (int r = 0; r < 4; ++r) {
      aR[r]  += w0[0][r][0] * xc0 + w0[0][r][1] * xc1 + w0[0][r][2] * xc2 + w0[0][r][3] * xc3;
      aZ[r]  += w0[1][r][0] * xc0 + w0[1][r][1] * xc1 + w0[1][r][2] * xc2 + w0[1][r][3] * xc3;
      aNx[r] += w0[2][r][0] * xc0 + w0[2][r][1] * xc1 + w0[2][r][2] * xc2 + w0[2][r][3] * xc3;
    }
    aR  = MFMA16(whh[0][0], hh0, aR);  aR  = MFMA16(whh[0][1], hh1, aR);
    aZ  = MFMA16(whh[1][0], hh0, aZ);  aZ  = MFMA16(whh[1][1], hh1, aZ);
    aNh = MFMA16(whh[2][0], hh0, aNh); aNh = MFMA16(whh[2][1], hh1, aNh);
    aR  = MFMA16(whl[0][0], hh0, aR);  aR  = MFMA16(whl[0][1], hh1, aR);
    aZ  = MFMA16(whl[1][0], hh0, aZ);  aZ  = MFMA16(whl[1][1], hh1, aZ);
    aNh = MFMA16(whl[2][0], hh0, aNh); aNh = MFMA16(whl[2][1], hh1, aNh);
    aR  = MFMA16(whh[0][0], hl0, aR);  aR  = MFMA16(whh[0][1], hl1, aR);
    aZ  = MFMA16(whh[1][0], hl0, aZ);  aZ  = MFMA16(whh[1][1], hl1, aZ);
    aNh = MFMA16(whh[2][0], hl0, aNh); aNh = MFMA16(whh[2][1], hl1, aNh);

    #pragma unroll
    for (int r = 0; r < 4; ++r) {
      float rr = sigm(aR[r]);
      float zz = sigm(aZ[r]);
      float nn = tanh_f(aNx[r] + rr * aNh[r]);
      h[r] = nn + zz * (h[r] - nn);
    }

    us4 hiw, low;
    #pragma unroll
    for (int r = 0; r < 4; ++r) {
      unsigned int u = __float_as_uint(h[r]);
      hiw[r] = (unsigned short)(u >> 16);
      float res = h[r] - __uint_as_float(u & 0xffff0000u);
      low[r] = (unsigned short)(__float_as_uint(res) >> 16);
    }
    const int q = (t + 1) & 1;
    *(us4*)&hbuf[q][0][n15][mu] = hiw;
    *(us4*)&hbuf[q][1][n15][mu] = low;

    us4 yw;
    #pragma unroll
    for (int r = 0; r < 4; ++r) yw[r] = f2bf_rne(h[r]);
    *(us4*)(xb + (size_t)t * 1024 + n15 * 64 + mu) = yw;
    __syncthreads();
  }
}

// ---------------- FC head ----------------
__global__ __launch_bounds__(128) void head(
    const float* __restrict__ hlast,
    const float* __restrict__ W1, const float* __restrict__ b1,
    const float* __restrict__ g1, const float* __restrict__ be1,
    const float* __restrict__ m1, const float* __restrict__ v1,
    const float* __restrict__ W2, const float* __restrict__ b2,
    const float* __restrict__ g2, const float* __restrict__ be2,
    const float* __restrict__ m2, const float* __restrict__ v2,
    const float* __restrict__ W3, const float* __restrict__ b3,
    float* __restrict__ out) {
  const int b = blockIdx.x;
  const int j = threadIdx.x;
  __shared__ float xin[128];
  __shared__ float y1[128];
  __shared__ float y2[128];
  xin[j] = (j < 64) ? hlast[(size_t)b * 64 + j]
                    : hlast[(size_t)BB * 64 + (size_t)b * 64 + (j - 64)];
  __syncthreads();
  float acc = b1[j];
  #pragma unroll 8
  for (int k = 0; k < 128; ++k) acc = fmaf(W1[j * 128 + k], xin[k], acc);
  float sc = g1[j] * rsqrtf(v1[j] + 1e-5f);
  y1[j] = fmaxf(0.f, (acc - m1[j]) * sc + be1[j]);
  __syncthreads();
  acc = b2[j];
  #pragma unroll 8
  for (int k = 0; k < 128; ++k) acc = fmaf(W2[j * 128 + k], y1[k], acc);
  sc = g2[j] * rsqrtf(v2[j] + 1e-5f);
  y2[j] = fmaxf(0.f, (acc - m2[j]) * sc + be2[j]);
  __syncthreads();
  if (j < 2) {
    float a = b3[j];
    #pragma unroll 8
    for (int k = 0; k < 128; ++k) a = fmaf(W3[j * 128 + k], y2[k], a);
    out[(size_t)b * 2 + j] = a;
  }
}

}  // namespace

extern "C" void kernel_launch(void* const* d_in, const int* in_sizes, int n_in,
                              void* d_out, int out_size, void* d_ws, size_t ws_size,
                              hipStream_t stream) {
  (void)in_sizes; (void)n_in; (void)out_size; (void)ws_size;
  const float* sent   = (const float*)d_in[0];
  const float* price  = (const float*)d_in[1];
  const float* s_Wih0 = (const float*)d_in[2];
  const float* s_Wih  = (const float*)d_in[3];
  const float* s_Whh  = (const float*)d_in[4];
  const float* s_bih  = (const float*)d_in[5];
  const float* s_bhh  = (const float*)d_in[6];
  const float* p_Wih0 = (const float*)d_in[7];
  const float* p_Wih  = (const float*)d_in[8];
  const float* p_Whh  = (const float*)d_in[9];
  const float* p_bih  = (const float*)d_in[10];
  const float* p_bhh  = (const float*)d_in[11];
  const float* fc1_W  = (const float*)d_in[12];
  const float* fc1_b  = (const float*)d_in[13];
  const float* bn1_g  = (const float*)d_in[14];
  const float* bn1_b  = (const float*)d_in[15];
  const float* bn1_m  = (const float*)d_in[16];
  const float* bn1_v  = (const float*)d_in[17];
  const float* fc2_W  = (const float*)d_in[18];
  const float* fc2_b  = (const float*)d_in[19];
  const float* bn2_g  = (const float*)d_in[20];
  const float* bn2_b  = (const float*)d_in[21];
  const float* bn2_m  = (const float*)d_in[22];
  const float* bn2_v  = (const float*)d_in[23];
  const float* fc3_W  = (const float*)d_in[24];
  const float* fc3_b  = (const float*)d_in[25];
  float* out = (float*)d_out;

  unsigned short* buf = (unsigned short*)d_ws;                  // [256 blk][256 t][16 n][64 u] bf16
  float* hlast = (float*)(buf + (size_t)256 * TT * 1024);       // [2,B,64] f32

  gru_l0<<<dim3(256), dim3(256), 0, stream>>>(
      sent, price, s_Wih0, p_Wih0, s_Whh, p_Whh,
      s_bih, s_bhh, p_bih, p_bhh, buf);

  for (int l = 1; l <= 3; ++l) {
    gru_ln<<<dim3(256), dim3(256), 0, stream>>>(
        s_Wih + (size_t)(l - 1) * 192 * 64, s_Whh + (size_t)l * 192 * 64,
        s_bih + l * 192, s_bhh + l * 192,
        p_Wih + (size_t)(l - 1) * 192 * 64, p_Whh + (size_t)l * 192 * 64,
        p_bih + l * 192, p_bhh + l * 192,
        buf, hlast, (l < 3) ? 1 : 0);
  }

  head<<<dim3(BB), dim3(128), 0, stream>>>(
      hlast, fc1_W, fc1_b, bn1_g, bn1_b, bn1_m, bn1_v,
      fc2_W, fc2_b, bn2_g, bn2_b, bn2_m, bn2_v, fc3_W, fc3_b, out);
}